// Round 5
// baseline (1220.314 us; speedup 1.0000x reference)
//
#include <hip/hip_runtime.h>
#include <hip/hip_bf16.h>

// Problem constants
#define L_SEQ 1024
#define N_B   64
#define D_H   256
#define D_W   300
#define LDK   72     // slow-path padded K-tile stride
#define LDH   264    // padded 256-K stride: 528B -> 2-way (free)

typedef __bf16 bf16x8 __attribute__((ext_vector_type(8)));
typedef float  f32x4  __attribute__((ext_vector_type(4)));
typedef unsigned short us8 __attribute__((ext_vector_type(8)));

#if defined(__has_builtin)
#if __has_builtin(__builtin_amdgcn_global_load_lds)
#define HAS_ASYNC_LDS 1
#endif
#endif

__device__ inline float b2f(unsigned short u){
    union { unsigned int i; float f; } v; v.i = ((unsigned int)u) << 16; return v.f;
}
__device__ inline unsigned short f2b(float f){
    union { float f; unsigned int i; } v; v.f = f;
    unsigned int u = v.i;
    return (unsigned short)((u + 0x7fffu + ((u >> 16) & 1u)) >> 16);
}
__device__ inline float sigf(float x){ return 1.0f / (1.0f + __expf(-x)); }
__device__ inline float tanhfast(float x){ return 1.0f - 2.0f / (__expf(2.0f*x) + 1.0f); }

// ---- dtype-agnostic loads: isf=1 -> fp32 data, isf=0 -> bf16 data ----
__device__ inline float ldf(const void* p, size_t i, int isf){
    return isf ? ((const float*)p)[i] : b2f(((const unsigned short*)p)[i]);
}
__device__ inline unsigned short ld1b(const void* p, size_t i, int isf){
    return isf ? f2b(((const float*)p)[i]) : ((const unsigned short*)p)[i];
}
__device__ inline us8 ld8(const void* p, size_t i, int isf){
    if (isf){
        const float* f = (const float*)p + i;
        float4 x = *(const float4*)f;
        float4 y = *(const float4*)(f + 4);
        us8 r = { f2b(x.x), f2b(x.y), f2b(x.z), f2b(x.w),
                  f2b(y.x), f2b(y.y), f2b(y.z), f2b(y.w) };
        return r;
    }
    return *(const us8*)((const unsigned short*)p + i);
}
__device__ inline unsigned int ld2(const void* p, size_t i, int isf){
    if (isf){
        const float* f = (const float*)p + i;
        float2 x = *(const float2*)f;
        return (unsigned int)f2b(x.x) | ((unsigned int)f2b(x.y) << 16);
    }
    return *(const unsigned int*)((const unsigned short*)p + i);
}
// 4-wide fp32-precision load (vectorized; no bf16 rounding on fp32 path)
__device__ inline float4 ldf4(const void* p, size_t i, int isf){
    if (isf) return *(const float4*)((const float*)p + i);
    unsigned long long v = *(const unsigned long long*)((const unsigned short*)p + i);
    float4 r;
    r.x = b2f((unsigned short)( v        & 0xffffu));
    r.y = b2f((unsigned short)((v >> 16) & 0xffffu));
    r.z = b2f((unsigned short)((v >> 32) & 0xffffu));
    r.w = b2f((unsigned short)( v >> 48));
    return r;
}

// async 16B/lane global->LDS; lds_base must be wave-uniform (HW adds lane*16)
__device__ inline void stage16(const unsigned short* g, unsigned short* lds_base, int lane){
#ifdef HAS_ASYNC_LDS
    __builtin_amdgcn_global_load_lds(
        (const __attribute__((address_space(1))) unsigned int*)g,
        (__attribute__((address_space(3))) unsigned int*)lds_base, 16, 0, 0);
#else
    *(us8*)(lds_base + lane*8) = *(const us8*)g;
#endif
}

// ---------------- dtype detector ----------------
__global__ __launch_bounds__(256) void k_detect(const void* __restrict__ h0, int* __restrict__ flag)
{
    int tid = threadIdx.x;
    const unsigned short* u = (const unsigned short*)h0;
    int cnt = 0;
    #pragma unroll
    for (int i = 0; i < 4; i++){
        unsigned short v = u[(size_t)(tid * 4 + i) * 2];
        int e = (v >> 7) & 0xFF;
        cnt += (e >= 90 && e <= 150) ? 1 : 0;
    }
    __shared__ int red[256];
    red[tid] = cnt;
    __syncthreads();
    for (int s = 128; s > 0; s >>= 1){
        if (tid < s) red[tid] += red[tid + s];
        __syncthreads();
    }
    if (tid == 0) flag[0] = (red[0] > 512) ? 0 : 1;
}

// ================= conversion kernels (fast path) =================
// hpad[i][b][d], i in [0,1028): i-2 = l; rows 0,1,1026,1027 zero; masked by slen.
__global__ __launch_bounds__(256) void k_conv_h(const void* __restrict__ h0,
    const int* __restrict__ slen, unsigned short* __restrict__ hpad, const int* __restrict__ flagp)
{
    int isf = flagp[0];
    int i = blockIdx.y;
    int idx = (blockIdx.x*256 + threadIdx.x)*8;
    int b = idx >> 8;
    int l = i - 2;
    us8 v = {0,0,0,0,0,0,0,0};
    if ((unsigned)l < 1024u && l < slen[b])
        v = ld8(h0, (size_t)l*16384 + idx, isf);
    *(us8*)(hpad + (size_t)i*16384 + idx) = v;
}

// srcpad[m][320], cols 300..320 zero
__global__ __launch_bounds__(256) void k_conv_src(const void* __restrict__ src,
    unsigned short* __restrict__ srcpad, const int* __restrict__ flagp)
{
    int isf = flagp[0];
    int gid = blockIdx.x*256 + threadIdx.x;   // < 65536*40
    int row = gid / 40, k = gid % 40, col = k*8;
    us8 v = {0,0,0,0,0,0,0,0};
    if (col + 8 <= 300) v = ld8(src, (size_t)row*300 + col, isf);
    else if (col < 300){
        for (int e = 0; e < 300 - col; ++e) v[e] = ld1b(src, (size_t)row*300 + col + e, isf);
    }
    *(us8*)(srcpad + (size_t)row*320 + col) = v;
}

// Wcat2[bx][h][rr][c]: bx = d>>4 (0..15), h = k>>5 (0..49), rr = g*16 + (d&15) (0..111),
// c = k&31. Per (bx,h) the 112x32 B-panel is contiguous (3584 shorts = 7168 B)
// -> coalesced staging in k_main_fast. k>=1280 maps to Wu (src weights).
__global__ __launch_bounds__(256) void k_conv_w(const void* __restrict__ Ww,
    const void* __restrict__ Wu, unsigned short* __restrict__ Wcat, const int* __restrict__ flagp)
{
    int isf = flagp[0];
    int gid = blockIdx.x*256 + threadIdx.x;   // < 16*50*112*4 = 358400
    int bx = gid / 22400, rem = gid % 22400;
    int h = rem / 448, rem2 = rem % 448;
    int rr = rem2 >> 2, c8 = rem2 & 3;
    int g = rr >> 4, d = bx*16 + (rr & 15);
    int k = h*32 + c8*8;
    size_t n = (size_t)g*256 + d;
    us8 v = {0,0,0,0,0,0,0,0};
    if (k < 1280) v = ld8(Ww, n*1280 + k, isf);
    else {
        int w = k - 1280;
        if (w + 8 <= 300) v = ld8(Wu, n*300 + w, isf);
        else if (w < 300){
            for (int e = 0; e < 300 - w; ++e) v[e] = ld1b(Wu, n*300 + w + e, isf);
        }
    }
    *(us8*)(Wcat + (size_t)gid*8) = v;
}

__global__ __launch_bounds__(256) void k_conv_su(const void* __restrict__ Su,
    unsigned short* __restrict__ Subf, const int* __restrict__ flagp)
{
    int isf = flagp[0];
    int gid = blockIdx.x*256 + threadIdx.x;
    *(us8*)(Subf + (size_t)gid*8) = ld8(Su, (size_t)65536 + (size_t)gid*8, isf);
}

// ---------------- h_hat partial sums from hpad (fast) ----------------
__global__ __launch_bounds__(256) void k_hhat_fast(const unsigned short* __restrict__ hpad,
    float* __restrict__ hhat)
{
    int b = blockIdx.x, part = blockIdx.y, d = threadIdx.x;
    float s = 0.f;
    const unsigned short* p = hpad + (size_t)(2 + part*128)*16384 + b*256 + d;
    for (int ll = 0; ll < 128; ++ll)
        s += b2f(p[(size_t)ll*16384]);
    atomicAdd(&hhat[b*256 + d], s);
}

// ---------------- h_hat (slow path) ----------------
__global__ __launch_bounds__(1024) void k_hhat(const void* __restrict__ h0,
    const int* __restrict__ slen, float* __restrict__ hhat, const int* __restrict__ flagp)
{
    int isf = flagp[0];
    int b = blockIdx.x;
    int part = threadIdx.x >> 8;
    int d = threadIdx.x & 255;
    int lenb = slen[b];
    float s = 0.f;
    for (int l = part; l < lenb; l += 4)
        s += ldf(h0, (size_t)l*16384 + b*256 + d, isf);
    __shared__ float red[1024];
    red[threadIdx.x] = s;
    __syncthreads();
    if (part == 0)
        hhat[b*256 + d] = (red[d] + red[d+256] + red[d+512] + red[d+768]);
}

// ---------------- fg, og, sg (global-cell small gates) ----------------
__global__ __launch_bounds__(256) void k_small(const void* __restrict__ h0,
    const float* __restrict__ hhat, const void* __restrict__ Sw,
    const void* __restrict__ Su, const void* __restrict__ Sb,
    float* __restrict__ fg, float* __restrict__ og, float* __restrict__ sg,
    const int* __restrict__ flagp, float hs)
{
    int isf = flagp[0];
    int b = blockIdx.x; int d = threadIdx.x;
    __shared__ float hgl[256], hhl[256];
    hgl[d] = ldf(h0, (size_t)16777216 + b*256 + d, isf);
    hhl[d] = hhat[b*256 + d] * hs;
    __syncthreads();
    size_t sw0 = (size_t)d*256, sw1 = (size_t)(256+d)*256, sw2 = (size_t)(512+d)*256;
    size_t su0 = (size_t)d*256, su2 = (size_t)(512+d)*256;
    float a0=0.f,a1=0.f,a2=0.f,a3=0.f,a4=0.f;
    #pragma unroll 4
    for (int h=0; h<256; h+=4){
        float4 w0 = ldf4(Sw, sw0+h, isf);
        float4 u0 = ldf4(Su, su0+h, isf);
        float4 w1 = ldf4(Sw, sw1+h, isf);
        float4 w2 = ldf4(Sw, sw2+h, isf);
        float4 u2 = ldf4(Su, su2+h, isf);
        float g0=hgl[h], g1=hgl[h+1], g2=hgl[h+2], g3=hgl[h+3];
        float q0=hhl[h], q1=hhl[h+1], q2=hhl[h+2], q3=hhl[h+3];
        a0 += g0*w0.x + g1*w0.y + g2*w0.z + g3*w0.w;
        a1 += q0*u0.x + q1*u0.y + q2*u0.z + q3*u0.w;
        a2 += g0*w1.x + g1*w1.y + g2*w1.z + g3*w1.w;
        a3 += g0*w2.x + g1*w2.y + g2*w2.z + g3*w2.w;
        a4 += q0*u2.x + q1*u2.y + q2*u2.z + q3*u2.w;
    }
    int i = b*256 + d;
    fg[i] = sigf(a0 + a1 + ldf(Sb, d, isf));
    sg[i] = a2 + ldf(Sb, 256 + d, isf);
    og[i] = sigf(a3 + a4 + ldf(Sb, 512 + d, isf));
}

// ---------------- hgWvB[b][g*256+d] = hg @ Wv[g].T + Wb ----------------
__global__ __launch_bounds__(256) void k_hgwv(const void* __restrict__ h0,
    const void* __restrict__ Wv, const void* __restrict__ Wb,
    float* __restrict__ hgWvB, const int* __restrict__ flagp)
{
    int isf = flagp[0];
    int b = blockIdx.x, g = blockIdx.y, d = threadIdx.x;
    __shared__ float hgl[256];
    hgl[d] = ldf(h0, (size_t)16777216 + b*256 + d, isf);
    __syncthreads();
    size_t wv = ((size_t)g*256 + d)*256;
    float a = 0.f;
    #pragma unroll 4
    for (int h=0; h<256; h+=4){
        float4 w = ldf4(Wv, wv+h, isf);
        a += hgl[h]*w.x + hgl[h+1]*w.y + hgl[h+2]*w.z + hgl[h+3]*w.w;
    }
    hgWvB[(size_t)b*1792 + g*256 + d] = a + ldf(Wb, g*256 + d, isf);
}

// ---------------- fi softmax num/den via MFMA — fast (bf16 hpad/Subf) ----------------
__global__ __launch_bounds__(256) void k_fi_fast(const unsigned short* __restrict__ hpad,
    const void* __restrict__ c0, const unsigned short* __restrict__ Subf,
    const int* __restrict__ slen, const float* __restrict__ sg,
    float* __restrict__ numv, float* __restrict__ denv, const int* __restrict__ flagp)
{
    int isf = flagp[0];
    __shared__ unsigned short Hs[64*LDH];
    int tid = threadIdx.x;
    int b = blockIdx.x;
    int l0 = blockIdx.y * 64;
    int lenb = slen[b];
    #pragma unroll
    for (int i=0;i<8;i++){
        int c = tid + i*256;
        int r = c >> 5;
        int col = (c & 31) << 3;
        *(us8*)(Hs + r*LDH + col) =
            *(const us8*)(hpad + (size_t)(l0 + r + 2)*16384 + b*256 + col);
    }
    __syncthreads();
    int wv = tid >> 6, lane = tid & 63, qd = lane >> 4, lc = lane & 15;
    f32x4 zero4 = {0.f,0.f,0.f,0.f};
    for (int dci=0; dci<4; ++dci){
        int d = (wv*4 + dci) * 16 + lc;
        f32x4 acc[4];
        #pragma unroll
        for (int t=0;t<4;t++) acc[t] = zero4;
        #pragma unroll
        for (int ks=0; ks<8; ++ks){
            int k0 = ks*32 + qd*8;
            bf16x8 bb = *(const bf16x8*)(Subf + (size_t)d*256 + k0);
            #pragma unroll
            for (int lt=0; lt<4; ++lt){
                bf16x8 aa = *(const bf16x8*)(Hs + (lt*16 + lc)*LDH + k0);
                acc[lt] = __builtin_amdgcn_mfma_f32_16x16x32_bf16(aa, bb, acc[lt], 0, 0, 0);
            }
        }
        float sgv = sg[b*256 + d];
        float pn = 0.f, pd = 0.f;
        #pragma unroll
        for (int lt=0; lt<4; ++lt){
            #pragma unroll
            for (int r=0; r<4; ++r){
                int l = l0 + lt*16 + qd*4 + r;
                if (l < lenb){
                    float e = __expf(sigf(acc[lt][r] + sgv));
                    pd += e;
                    pn += e * ldf(c0, (size_t)l*16384 + b*256 + d, isf);
                }
            }
        }
        pn += __shfl_xor(pn, 16); pn += __shfl_xor(pn, 32);
        pd += __shfl_xor(pd, 16); pd += __shfl_xor(pd, 32);
        if (qd == 0){
            atomicAdd(&numv[b*256 + d], pn);
            atomicAdd(&denv[b*256 + d], pd);
        }
    }
}

// ---------------- fi (slow path, raw inputs) ----------------
__global__ __launch_bounds__(256) void k_fi(const void* __restrict__ h0,
    const void* __restrict__ c0, const void* __restrict__ Su,
    const int* __restrict__ slen, const float* __restrict__ sg,
    float* __restrict__ numv, float* __restrict__ denv, const int* __restrict__ flagp)
{
    int isf = flagp[0];
    __shared__ unsigned short Hs[64*LDH];
    int tid = threadIdx.x;
    int b = blockIdx.x;
    int l0 = blockIdx.y * 64;
    int lenb = slen[b];
    #pragma unroll
    for (int i=0;i<8;i++){
        int c = tid + i*256;
        int r = c >> 5;
        int col = (c & 31) << 3;
        int l = l0 + r;
        us8 v = {0,0,0,0,0,0,0,0};
        if (l < lenb)
            v = ld8(h0, (size_t)l*16384 + b*256 + col, isf);
        *(us8*)(Hs + r*LDH + col) = v;
    }
    __syncthreads();
    int wv = tid >> 6, lane = tid & 63, qd = lane >> 4, lc = lane & 15;
    f32x4 zero4 = {0.f,0.f,0.f,0.f};
    for (int dci=0; dci<4; ++dci){
        int d = (wv*4 + dci) * 16 + lc;
        f32x4 acc[4];
        #pragma unroll
        for (int t=0;t<4;t++) acc[t] = zero4;
        #pragma unroll
        for (int ks=0; ks<8; ++ks){
            int k0 = ks*32 + qd*8;
            union { us8 u; bf16x8 b; } cv; cv.u = ld8(Su, (size_t)65536 + (size_t)d*256 + k0, isf);
            bf16x8 bb = cv.b;
            #pragma unroll
            for (int lt=0; lt<4; ++lt){
                bf16x8 aa = *(const bf16x8*)(Hs + (lt*16 + lc)*LDH + k0);
                acc[lt] = __builtin_amdgcn_mfma_f32_16x16x32_bf16(aa, bb, acc[lt], 0, 0, 0);
            }
        }
        float sgv = sg[b*256 + d];
        float pn = 0.f, pd = 0.f;
        #pragma unroll
        for (int lt=0; lt<4; ++lt){
            #pragma unroll
            for (int r=0; r<4; ++r){
                int l = l0 + lt*16 + qd*4 + r;
                if (l < lenb){
                    float e = __expf(sigf(acc[lt][r] + sgv));
                    pd += e;
                    pn += e * ldf(c0, (size_t)l*16384 + b*256 + d, isf);
                }
            }
        }
        pn += __shfl_xor(pn, 16); pn += __shfl_xor(pn, 32);
        pd += __shfl_xor(pd, 16); pd += __shfl_xor(pd, 32);
        if (qd == 0){
            atomicAdd(&numv[b*256 + d], pn);
            atomicAdd(&denv[b*256 + d], pd);
        }
    }
}

// ---------------- finalize global cell ----------------
__global__ __launch_bounds__(256) void k_cg(const void* __restrict__ c0,
    const float* __restrict__ fg, const float* __restrict__ og,
    const float* __restrict__ numv, const float* __restrict__ denv,
    float* __restrict__ outh, float* __restrict__ outc,
    const int* __restrict__ flagp)
{
    int isf = flagp[0];
    int i = blockIdx.x*256 + threadIdx.x;
    float cg1 = ldf(c0, (size_t)16777216 + i, isf);
    float cg = fg[i]*cg1 + numv[i]/denv[i];
    float hg = og[i]*tanhfast(cg);
    outh[(size_t)16777216 + i] = hg;
    outc[(size_t)16777216 + i] = cg;
}

// ================= fast main GEMM: B-in-LDS + A-in-reg depth-3 pipeline ==========
// grid (16, 256): bx = d-tile (d0 = bx*16), by = m-tile (m0 = by*256), BM=256, BK=32.
// B panel (7KB/phase, shared 4x across waves) staged via global_load_lds into a
// 2-buffer LDS ring (XOR-swizzled source, involution on read -> 2-way banks = free).
// A fragments (wave-exclusive, zero sharing) load global->reg at prefetch depth 3
// (sets rotate mod 3; phase p reloads its own set with A[p+3] after the MFMAs).
// One barrier per phase with counted s_waitcnt vmcnt(4) (B[p+1] landed; A[p+3] stays
// in flight) - never drained to 0 in steady state. 28 MFMA : 7 ds_read per phase.
__global__ __launch_bounds__(256, 2) void k_main_fast(
    const unsigned short* __restrict__ hpad, const unsigned short* __restrict__ srcpad,
    const unsigned short* __restrict__ Wcat, const void* __restrict__ c0,
    const int* __restrict__ slen, const float* __restrict__ hgWvB,
    float* __restrict__ outh, float* __restrict__ outc, const int* __restrict__ flagp)
{
    int isf = flagp[0];
    __shared__ unsigned short Bs[2][3584];   // 2 x 7168 B
    int tid = threadIdx.x;
    int d0 = blockIdx.x * 16;
    int m0 = blockIdx.y * 256;
    int wv = tid >> 6, lane = tid & 63, qd = lane >> 4, lc = lane & 15;

    // per-lane A row bases (wave owns rows m0+wv*64 .. +63; subtile t covers +t*16)
    int mr0 = m0 + wv*64 + lc;
    const unsigned short* pA0h = hpad + (size_t)(mr0      )*256 + qd*8;
    const unsigned short* pA1h = hpad + (size_t)(mr0 + 16 )*256 + qd*8;
    const unsigned short* pA2h = hpad + (size_t)(mr0 + 32 )*256 + qd*8;
    const unsigned short* pA3h = hpad + (size_t)(mr0 + 48 )*256 + qd*8;
    const unsigned short* pA0s = srcpad + (size_t)(mr0      )*320 + qd*8;
    const unsigned short* pA1s = srcpad + (size_t)(mr0 + 16 )*320 + qd*8;
    const unsigned short* pA2s = srcpad + (size_t)(mr0 + 32 )*320 + qd*8;
    const unsigned short* pA3s = srcpad + (size_t)(mr0 + 48 )*320 + qd*8;

    // B global panel base (Wcat2: per (bx, phase) 112x32 contiguous)
    const unsigned short* gB = Wcat + (size_t)blockIdx.x * 50 * 3584;

    // staging: pre-swizzled global source so linear LDS dest ends up chunk-XOR'd.
    // LDS 16B-chunk p (row rr=p>>2, slot p&3) holds global chunk (p&3)^((rr>>1)&3)
    int p0c = wv*64 + lane;
    int rr0s = p0c >> 2, cl0s = p0c & 3;
    int soff0 = rr0s*32 + ((cl0s ^ ((rr0s >> 1) & 3)) << 3);
    int p1c = 256 + wv*64 + lane;
    int rr1s = p1c >> 2, cl1s = p1c & 3;
    int soff1 = rr1s*32 + ((cl1s ^ ((rr1s >> 1) & 3)) << 3);

    // ds_read offsets: row rr = g*16+lc, chunk qd ^ ((rr>>1)&3); (rr>>1)&3 == (lc>>1)&3
    int bch = ((qd ^ ((lc >> 1) & 3)) << 3);
    int bro0 = (0*16 + lc)*32 + bch;
    int bro1 = (1*16 + lc)*32 + bch;
    int bro2 = (2*16 + lc)*32 + bch;
    int bro3 = (3*16 + lc)*32 + bch;
    int bro4 = (4*16 + lc)*32 + bch;
    int bro5 = (5*16 + lc)*32 + bch;
    int bro6 = (6*16 + lc)*32 + bch;

    f32x4 zero4 = {0.f,0.f,0.f,0.f};
    f32x4 acc[4][7];
    #pragma unroll
    for (int a=0;a<4;a++)
        #pragma unroll
        for (int g=0;g<7;g++) acc[a][g] = zero4;

    bf16x8 A0_0, A0_1, A0_2, A0_3;
    bf16x8 A1_0, A1_1, A1_2, A1_3;
    bf16x8 A2_0, A2_1, A2_2, A2_3;

#define STAGE_B(p_) do {                                                         \
        const unsigned short* gp_ = gB + (size_t)(p_) * 3584;                    \
        unsigned short* lbW_ = &Bs[(p_) & 1][0];                                 \
        stage16(gp_ + soff0, lbW_ + wv*512, lane);                               \
        if (tid < 192) stage16(gp_ + soff1, lbW_ + 2048 + wv*512, lane);         \
    } while(0)

#define LOAD_A(S_, q_) do {                                                      \
        int qq_ = (q_);                                                          \
        if (qq_ < 40){                                                           \
            int off_ = ((qq_ >> 3) << 14) + ((qq_ & 7) << 5);                    \
            S_##_0 = *(const bf16x8*)(pA0h + off_);                              \
            S_##_1 = *(const bf16x8*)(pA1h + off_);                              \
            S_##_2 = *(const bf16x8*)(pA2h + off_);                              \
            S_##_3 = *(const bf16x8*)(pA3h + off_);                              \
        } else {                                                                 \
            int off_ = (qq_ - 40) << 5;                                          \
            S_##_0 = *(const bf16x8*)(pA0s + off_);                              \
            S_##_1 = *(const bf16x8*)(pA1s + off_);                              \
            S_##_2 = *(const bf16x8*)(pA2s + off_);                              \
            S_##_3 = *(const bf16x8*)(pA3s + off_);                              \
        }                                                                        \
    } while(0)

#define MG(S_, vb_, g_) do {                                                     \
        acc[0][g_] = __builtin_amdgcn_mfma_f32_16x16x32_bf16(S_##_0, vb_, acc[0][g_],0,0,0); \
        acc[1][g_] = __builtin_amdgcn_mfma_f32_16x16x32_bf16(S_##_1, vb_, acc[1][g_],0,0,0); \
        acc[2][g_] = __builtin_amdgcn_mfma_f32_16x16x32_bf16(S_##_2, vb_, acc[2][g_],0,0,0); \
        acc[3][g_] = __builtin_amdgcn_mfma_f32_16x16x32_bf16(S_##_3, vb_, acc[3][g_],0,0,0); \
    } while(0)

    // Phase p: ds_read 7 B frags (buf p&1) | stage B[p+1] | 28 MFMA | reload A-set
    // with A[p+3] | vmcnt(WN) + barrier. VMEM issue order per phase is pinned by the
    // asm memory fences: [stage(2) ... A-loads(4)] so vmcnt(4) confirms B[p+1].
#define PHASE(p_, S_, WN_, LAST_) do {                                           \
        const unsigned short* lb_ = &Bs[(p_) & 1][0];                            \
        bf16x8 vb0 = *(const bf16x8*)(lb_ + bro0);                               \
        bf16x8 vb1 = *(const bf16x8*)(lb_ + bro1);                               \
        bf16x8 vb2 = *(const bf16x8*)(lb_ + bro2);                               \
        bf16x8 vb3 = *(const bf16x8*)(lb_ + bro3);                               \
        bf16x8 vb4 = *(const bf16x8*)(lb_ + bro4);                               \
        bf16x8 vb5 = *(const bf16x8*)(lb_ + bro5);                               \
        bf16x8 vb6 = *(const bf16x8*)(lb_ + bro6);                               \
        if ((p_) + 1 < 50) STAGE_B((p_) + 1);                                    \
        asm volatile("" ::: "memory");                                           \
        __builtin_amdgcn_s_setprio(1);                                           \
        MG(S_, vb0, 0); MG(S_, vb1, 1); MG(S_, vb2, 2); MG(S_, vb3, 3);          \
        MG(S_, vb4, 4); MG(S_, vb5, 5); MG(S_, vb6, 6);                          \
        __builtin_amdgcn_s_setprio(0);                                           \
        if ((p_) + 3 < 50) LOAD_A(S_, (p_) + 3);                                 \
        if (!(LAST_)){                                                           \
            asm volatile("s_waitcnt vmcnt(" WN_ ")" ::: "memory");               \
            __builtin_amdgcn_s_barrier();                                        \
            asm volatile("" ::: "memory");                                       \
        }                                                                        \
    } while(0)

    // prologue: B[0] staged, A[0..2] in flight; confirm only B[0] (vmcnt(12))
    STAGE_B(0);
    LOAD_A(A0, 0); LOAD_A(A1, 1); LOAD_A(A2, 2);
    asm volatile("s_waitcnt vmcnt(12)" ::: "memory");
    __builtin_amdgcn_s_barrier();
    asm volatile("" ::: "memory");

    for (int h = 0; h < 45; h += 3){
        PHASE(h + 0, A0, "4", 0);
        PHASE(h + 1, A1, "4", 0);
        PHASE(h + 2, A2, "4", 0);
    }
    PHASE(45, A0, "4", 0);
    PHASE(46, A1, "4", 0);
    PHASE(47, A2, "0", 0);   // A[50] skipped -> drain to confirm B[48]
    PHASE(48, A0, "0", 0);   // confirm B[49]
    PHASE(49, A1, "0", 1);   // final phase, no barrier

#undef PHASE
#undef MG
#undef LOAD_A
#undef STAGE_B

    // Fused gate epilogue (4 m-subtiles per wave)
    int d = d0 + lc;
    #pragma unroll
    for (int mt=0; mt<4; ++mt){
        #pragma unroll
        for (int r=0; r<4; ++r){
            int m = m0 + wv*64 + mt*16 + qd*4 + r;
            int l = m >> 6, b = m & 63;
            size_t oi = (size_t)m*256 + d;
            int lenb = slen[b];
            float hw = 0.f, cw = 0.f;
            if (l < lenb){
                const float* hv = hgWvB + (size_t)b*1792 + d;
                float p0 = acc[mt][0][r] + hv[0];
                float p1 = acc[mt][1][r] + hv[256];
                float p2 = acc[mt][2][r] + hv[512];
                float p3 = acc[mt][3][r] + hv[768];
                float p4 = acc[mt][4][r] + hv[1024];
                float p5 = acc[mt][5][r] + hv[1280];
                float p6 = acc[mt][6][r] + hv[1536];
                float e_l = __expf(sigf(p1));
                float e_f = __expf(sigf(p3));
                float e_r = __expf(sigf(p2));
                float e_s = __expf(sigf(p4));
                float e_i = __expf(sigf(p0));
                float S = e_l + e_f + e_r + e_s + e_i;
                float u_ = tanhfast(p6);
                float cl = (l >= 1) ? ldf(c0, oi - 16384, isf) : 0.f;
                float cc = ldf(c0, oi, isf);
                float cr = (l + 1 < lenb) ? ldf(c0, oi + 16384, isf) : 0.f;
                float cg1 = ldf(c0, (size_t)16777216 + b*256 + d, isf);
                cw = (e_l*cl + e_f*cc + e_r*cr + e_s*cg1 + e_i*u_) / S;
                hw = sigf(p5) * tanhfast(cw);
            }
            outh[oi] = hw;
            outc[oi] = cw;
        }
    }
}

// ================= slow main GEMM (fallback, raw inputs) =================
__global__ __launch_bounds__(256) void k_main(
    const void* __restrict__ src, const void* __restrict__ h0,
    const void* __restrict__ c0, const void* __restrict__ Ww,
    const void* __restrict__ Wu, const int* __restrict__ slen,
    const float* __restrict__ hgWvB,
    float* __restrict__ outh, float* __restrict__ outc,
    const int* __restrict__ flagp)
{
    int isf = flagp[0];
    __shared__ unsigned short As[128*LDK];
    __shared__ unsigned short Bs[112*LDK];
    int tid = threadIdx.x;
    int m0 = blockIdx.x * 128;
    int d0 = blockIdx.y * 16;
    int wv = tid >> 6, lane = tid & 63, qd = lane >> 4, lc = lane & 15;

    int ar[4], acol[4], al[4], ab[4], alen[4];
    #pragma unroll
    for (int i=0;i<4;i++){
        int c = tid + i*256;
        ar[i] = c >> 3; acol[i] = (c & 7) << 3;
        int m = m0 + ar[i];
        al[i] = m >> 6; ab[i] = m & 63;
        alen[i] = slen[ab[i]];
    }

    f32x4 zero4 = {0.f,0.f,0.f,0.f};
    f32x4 acc[2][7];
    #pragma unroll
    for (int a=0;a<2;a++)
        #pragma unroll
        for (int g=0;g<7;g++) acc[a][g] = zero4;

    for (int kt=0; kt<25; ++kt){
        __syncthreads();
        if (kt < 20){
            int j = kt >> 2;
            int koff = (kt & 3) << 6;
            #pragma unroll
            for (int i=0;i<4;i++){
                int lp = al[i] + j - 2;
                us8 v = {0,0,0,0,0,0,0,0};
                if ((unsigned)lp < 1024u && lp < alen[i])
                    v = ld8(h0, (size_t)lp*16384 + ab[i]*256 + koff + acol[i], isf);
                *(us8*)(As + ar[i]*LDK + acol[i]) = v;
            }
            #pragma unroll
            for (int i=0;i<4;i++){
                int c = tid + i*256;
                if (c < 896){
                    int rr = c >> 3, col = (c & 7) << 3;
                    int g = rr >> 4, d = d0 + (rr & 15);
                    *(us8*)(Bs + rr*LDK + col) =
                        ld8(Ww, ((size_t)g*256 + d)*1280 + j*256 + koff + col, isf);
                }
            }
        } else {
            int w0 = (kt - 20) << 6;
            #pragma unroll
            for (int i=0;i<16;i++){
                int c = tid + i*256;
                int r = c >> 5, wi = (c & 31) << 1;
                int w = w0 + wi;
                int m = m0 + r;
                unsigned int v = 0;
                if (w < 300) v = ld2(src, (size_t)m*300 + w, isf);
                *(unsigned int*)(As + r*LDK + wi) = v;
            }
            #pragma unroll
            for (int i=0;i<14;i++){
                int c = tid + i*256;
                int rr = c >> 5, wi = (c & 31) << 1;
                int w = w0 + wi;
                int g = rr >> 4, d = d0 + (rr & 15);
                unsigned int v = 0;
                if (w < 300) v = ld2(Wu, ((size_t)g*256 + d)*300 + w, isf);
                *(unsigned int*)(Bs + rr*LDK + wi) = v;
            }
        }
        __syncthreads();
        #pragma unroll
        for (int ks=0; ks<2; ++ks){
            int k0 = (ks << 5) + (qd << 3);
            bf16x8 a0 = *(const bf16x8*)(As + (wv*32 + lc)*LDK + k0);
            bf16x8 a1 = *(const bf16x8*)(As + (wv*32 + 16 + lc)*LDK + k0);
            #pragma unroll
            for (int g=0; g<7; ++g){
                bf16x8 bg = *(const bf16x8*)(Bs + (g*16 + lc)*LDK + k0);
                acc[0][g] = __builtin_amdgcn_mfma_f32_16x16x32_bf16(a0, bg, acc[0][g], 0,0,0);
                acc[1][g] = __builtin_amdgcn_mfma_f32_16x16x32_bf16(a1, bg, acc[1][g], 0,0,0);
            }
        }
    }

    int d = d0 + lc;
    #pragma unroll
    for (int mt=0; mt<2; ++mt){
        #pragma unroll
        for (int r=0; r<4; ++r){
            int m = m0 + wv*32 + mt*16 + qd*4 + r;
            int l = m >> 6, b = m & 63;
            size_t oi = (size_t)m*256 + d;
            int lenb = slen[b];
            float hw = 0.f, cw = 0.f;
            if (l < lenb){
                const float* hv = hgWvB + (size_t)b*1792 + d;
                float p0 = acc[mt][0][r] + hv[0];
                float p1 = acc[mt][1][r] + hv[256];
                float p2 = acc[mt][2][r] + hv[512];
                float p3 = acc[mt][3][r] + hv[768];
                float p4 = acc[mt][4][r] + hv[1024];
                float p5 = acc[mt][5][r] + hv[1280];
                float p6 = acc[mt][6][r] + hv[1536];
                float e_l = __expf(sigf(p1));
                float e_f = __expf(sigf(p3));
                float e_r = __expf(sigf(p2));
                float e_s = __expf(sigf(p4));
                float e_i = __expf(sigf(p0));
                float S = e_l + e_f + e_r + e_s + e_i;
                float u_ = tanhfast(p6);
                float cl = (l >= 1) ? ldf(c0, oi - 16384, isf) : 0.f;
                float cc = ldf(c0, oi, isf);
                float cr = (l + 1 < lenb) ? ldf(c0, oi + 16384, isf) : 0.f;
                float cg1 = ldf(c0, (size_t)16777216 + b*256 + d, isf);
                cw = (e_l*cl + e_f*cc + e_r*cr + e_s*cg1 + e_i*u_) / S;
                hw = sigf(p5) * tanhfast(cw);
            }
            outh[oi] = hw;
            outc[oi] = cw;
        }
    }
}

extern "C" void kernel_launch(void* const* d_in, const int* in_sizes, int n_in,
                              void* d_out, int out_size, void* d_ws, size_t ws_size,
                              hipStream_t stream)
{
    const void* src = d_in[0];
    const void* h0  = d_in[1];
    const void* c0  = d_in[2];
    const void* Ww  = d_in[3];
    const void* Wu  = d_in[4];
    const void* Wv  = d_in[5];
    const void* Wb  = d_in[6];
    const void* Sw  = d_in[7];
    const void* Su  = d_in[8];
    const void* Sb  = d_in[9];
    const int* slen = (const int*)d_in[10];

    float* outh = (float*)d_out;
    float* outc = outh + (size_t)1025*64*256;

    float* ws    = (float*)d_ws;
    float* numv  = ws;
    float* denv  = ws + 16384;
    float* hhat  = ws + 32768;
    float* fg    = ws + 49152;
    float* og    = ws + 65536;
    float* sg    = ws + 81920;
    float* hgWvB = ws + 98304;            // 64*1792 floats -> ends 212992
    int*   flag  = (int*)(ws + 212992);   // 16 floats reserved

    unsigned short* bfbase = (unsigned short*)(ws + 213024);
    unsigned short* hpad   = bfbase;                       // 1028*16384
    unsigned short* srcpad = bfbase + (size_t)16842752;    // 65536*320
    unsigned short* Wcat   = bfbase + (size_t)37814272;    // 16*50*112*32 = 2867200
    unsigned short* Subf   = bfbase + (size_t)40681472;    // 256*256
    const size_t NEED = 852096 + (size_t)40747008*2;       // 82,346,112 B

    hipLaunchKernelGGL(k_detect, dim3(1), dim3(256), 0, stream, h0, flag);
    hipMemsetAsync(ws, 0, (size_t)3*16384*sizeof(float), stream);   // numv, denv, hhat

    if (ws_size >= NEED){
        hipLaunchKernelGGL(k_conv_h,  dim3(8,1028), dim3(256), 0, stream, h0, slen, hpad, flag);
        hipLaunchKernelGGL(k_conv_src, dim3(10240), dim3(256), 0, stream, src, srcpad, flag);
        hipLaunchKernelGGL(k_conv_w,   dim3(1400),  dim3(256), 0, stream, Ww, Wu, Wcat, flag);
        hipLaunchKernelGGL(k_conv_su,  dim3(32),    dim3(256), 0, stream, Su, Subf, flag);
        hipLaunchKernelGGL(k_hhat_fast, dim3(64,8), dim3(256), 0, stream, hpad, hhat);
        hipLaunchKernelGGL(k_small, dim3(64), dim3(256), 0, stream, h0, hhat, Sw, Su, Sb,
                           fg, og, sg, flag, 1.0f/1024.0f);
        hipLaunchKernelGGL(k_hgwv, dim3(64,7), dim3(256), 0, stream, h0, Wv, Wb, hgWvB, flag);
        hipLaunchKernelGGL(k_fi_fast, dim3(64,16), dim3(256), 0, stream, hpad, c0, Subf, slen,
                           sg, numv, denv, flag);
        hipLaunchKernelGGL(k_cg, dim3(64), dim3(256), 0, stream, c0, fg, og, numv, denv,
                           outh, outc, flag);
        hipLaunchKernelGGL(k_main_fast, dim3(16,256), dim3(256), 0, stream,
                           hpad, srcpad, Wcat, c0, slen, hgWvB, outh, outc, flag);
    } else {
        hipLaunchKernelGGL(k_hhat, dim3(64), dim3(1024), 0, stream, h0, slen, hhat, flag);
        hipLaunchKernelGGL(k_small, dim3(64), dim3(256), 0, stream, h0, hhat, Sw, Su, Sb,
                           fg, og, sg, flag, 1.0f/1024.0f);
        hipLaunchKernelGGL(k_hgwv, dim3(64,7), dim3(256), 0, stream, h0, Wv, Wb, hgWvB, flag);
        hipLaunchKernelGGL(k_fi, dim3(64,16), dim3(256), 0, stream, h0, c0, Su, slen,
                           sg, numv, denv, flag);
        hipLaunchKernelGGL(k_cg, dim3(64), dim3(256), 0, stream, c0, fg, og, numv, denv,
                           outh, outc, flag);
        hipLaunchKernelGGL(k_main, dim3(512,16), dim3(256), 0, stream,
                           src, h0, c0, Ww, Wu, slen, hgWvB, outh, outc, flag);
    }
}

// Round 6
// 854.925 us; speedup vs baseline: 1.4274x; 1.4274x over previous
//
#include <hip/hip_runtime.h>
#include <hip/hip_bf16.h>

// Problem constants
#define L_SEQ 1024
#define N_B   64
#define D_H   256
#define D_W   300
#define LDK   72     // slow-path padded K-tile stride
#define LDH   264    // padded 256-K stride: 528B -> 2-way (free)

typedef __bf16 bf16x8 __attribute__((ext_vector_type(8)));
typedef float  f32x4  __attribute__((ext_vector_type(4)));
typedef unsigned short us8 __attribute__((ext_vector_type(8)));

#if defined(__has_builtin)
#if __has_builtin(__builtin_amdgcn_global_load_lds)
#define HAS_ASYNC_LDS 1
#endif
#endif

__device__ inline float b2f(unsigned short u){
    union { unsigned int i; float f; } v; v.i = ((unsigned int)u) << 16; return v.f;
}
__device__ inline unsigned short f2b(float f){
    union { float f; unsigned int i; } v; v.f = f;
    unsigned int u = v.i;
    return (unsigned short)((u + 0x7fffu + ((u >> 16) & 1u)) >> 16);
}
__device__ inline float sigf(float x){ return 1.0f / (1.0f + __expf(-x)); }
__device__ inline float tanhfast(float x){ return 1.0f - 2.0f / (__expf(2.0f*x) + 1.0f); }

// ---- dtype-agnostic loads: isf=1 -> fp32 data, isf=0 -> bf16 data ----
__device__ inline float ldf(const void* p, size_t i, int isf){
    return isf ? ((const float*)p)[i] : b2f(((const unsigned short*)p)[i]);
}
__device__ inline unsigned short ld1b(const void* p, size_t i, int isf){
    return isf ? f2b(((const float*)p)[i]) : ((const unsigned short*)p)[i];
}
__device__ inline us8 ld8(const void* p, size_t i, int isf){
    if (isf){
        const float* f = (const float*)p + i;
        float4 x = *(const float4*)f;
        float4 y = *(const float4*)(f + 4);
        us8 r = { f2b(x.x), f2b(x.y), f2b(x.z), f2b(x.w),
                  f2b(y.x), f2b(y.y), f2b(y.z), f2b(y.w) };
        return r;
    }
    return *(const us8*)((const unsigned short*)p + i);
}
__device__ inline unsigned int ld2(const void* p, size_t i, int isf){
    if (isf){
        const float* f = (const float*)p + i;
        float2 x = *(const float2*)f;
        return (unsigned int)f2b(x.x) | ((unsigned int)f2b(x.y) << 16);
    }
    return *(const unsigned int*)((const unsigned short*)p + i);
}
// 4-wide fp32-precision load (vectorized; no bf16 rounding on fp32 path)
__device__ inline float4 ldf4(const void* p, size_t i, int isf){
    if (isf) return *(const float4*)((const float*)p + i);
    unsigned long long v = *(const unsigned long long*)((const unsigned short*)p + i);
    float4 r;
    r.x = b2f((unsigned short)( v        & 0xffffu));
    r.y = b2f((unsigned short)((v >> 16) & 0xffffu));
    r.z = b2f((unsigned short)((v >> 32) & 0xffffu));
    r.w = b2f((unsigned short)( v >> 48));
    return r;
}

// async 16B/lane global->LDS; lds_base must be wave-uniform (HW adds lane*16)
__device__ inline void stage16(const unsigned short* g, unsigned short* lds_base, int lane){
#ifdef HAS_ASYNC_LDS
    __builtin_amdgcn_global_load_lds(
        (const __attribute__((address_space(1))) unsigned int*)g,
        (__attribute__((address_space(3))) unsigned int*)lds_base, 16, 0, 0);
#else
    *(us8*)(lds_base + lane*8) = *(const us8*)g;
#endif
}

// ---------------- dtype detector ----------------
__global__ __launch_bounds__(256) void k_detect(const void* __restrict__ h0, int* __restrict__ flag)
{
    int tid = threadIdx.x;
    const unsigned short* u = (const unsigned short*)h0;
    int cnt = 0;
    #pragma unroll
    for (int i = 0; i < 4; i++){
        unsigned short v = u[(size_t)(tid * 4 + i) * 2];
        int e = (v >> 7) & 0xFF;
        cnt += (e >= 90 && e <= 150) ? 1 : 0;
    }
    __shared__ int red[256];
    red[tid] = cnt;
    __syncthreads();
    for (int s = 128; s > 0; s >>= 1){
        if (tid < s) red[tid] += red[tid + s];
        __syncthreads();
    }
    if (tid == 0) flag[0] = (red[0] > 512) ? 0 : 1;
}

// ================= conversion kernels (fast path) =================
// hpad[i][b][d], i in [0,1028): i-2 = l; rows 0,1,1026,1027 zero; masked by slen.
__global__ __launch_bounds__(256) void k_conv_h(const void* __restrict__ h0,
    const int* __restrict__ slen, unsigned short* __restrict__ hpad, const int* __restrict__ flagp)
{
    int isf = flagp[0];
    int i = blockIdx.y;
    int idx = (blockIdx.x*256 + threadIdx.x)*8;
    int b = idx >> 8;
    int l = i - 2;
    us8 v = {0,0,0,0,0,0,0,0};
    if ((unsigned)l < 1024u && l < slen[b])
        v = ld8(h0, (size_t)l*16384 + idx, isf);
    *(us8*)(hpad + (size_t)i*16384 + idx) = v;
}

// srcpad[m][320], cols 300..320 zero
__global__ __launch_bounds__(256) void k_conv_src(const void* __restrict__ src,
    unsigned short* __restrict__ srcpad, const int* __restrict__ flagp)
{
    int isf = flagp[0];
    int gid = blockIdx.x*256 + threadIdx.x;   // < 65536*40
    int row = gid / 40, k = gid % 40, col = k*8;
    us8 v = {0,0,0,0,0,0,0,0};
    if (col + 8 <= 300) v = ld8(src, (size_t)row*300 + col, isf);
    else if (col < 300){
        for (int e = 0; e < 300 - col; ++e) v[e] = ld1b(src, (size_t)row*300 + col + e, isf);
    }
    *(us8*)(srcpad + (size_t)row*320 + col) = v;
}

// Wcat2[bx][h][rr][c]: bx = d>>4 (0..15), h = k>>5 (0..49), rr = g*16 + (d&15) (0..111),
// c = k&31. Per (bx,h) the 112x32 B-panel is contiguous (3584 shorts = 7168 B)
// -> coalesced staging in k_main_fast. k>=1280 maps to Wu (src weights).
__global__ __launch_bounds__(256) void k_conv_w(const void* __restrict__ Ww,
    const void* __restrict__ Wu, unsigned short* __restrict__ Wcat, const int* __restrict__ flagp)
{
    int isf = flagp[0];
    int gid = blockIdx.x*256 + threadIdx.x;   // < 16*50*112*4 = 358400
    int bx = gid / 22400, rem = gid % 22400;
    int h = rem / 448, rem2 = rem % 448;
    int rr = rem2 >> 2, c8 = rem2 & 3;
    int g = rr >> 4, d = bx*16 + (rr & 15);
    int k = h*32 + c8*8;
    size_t n = (size_t)g*256 + d;
    us8 v = {0,0,0,0,0,0,0,0};
    if (k < 1280) v = ld8(Ww, n*1280 + k, isf);
    else {
        int w = k - 1280;
        if (w + 8 <= 300) v = ld8(Wu, n*300 + w, isf);
        else if (w < 300){
            for (int e = 0; e < 300 - w; ++e) v[e] = ld1b(Wu, n*300 + w + e, isf);
        }
    }
    *(us8*)(Wcat + (size_t)gid*8) = v;
}

__global__ __launch_bounds__(256) void k_conv_su(const void* __restrict__ Su,
    unsigned short* __restrict__ Subf, const int* __restrict__ flagp)
{
    int isf = flagp[0];
    int gid = blockIdx.x*256 + threadIdx.x;
    *(us8*)(Subf + (size_t)gid*8) = ld8(Su, (size_t)65536 + (size_t)gid*8, isf);
}

// ---------------- h_hat partial sums from hpad (fast) ----------------
__global__ __launch_bounds__(256) void k_hhat_fast(const unsigned short* __restrict__ hpad,
    float* __restrict__ hhat)
{
    int b = blockIdx.x, part = blockIdx.y, d = threadIdx.x;
    float s = 0.f;
    const unsigned short* p = hpad + (size_t)(2 + part*128)*16384 + b*256 + d;
    for (int ll = 0; ll < 128; ++ll)
        s += b2f(p[(size_t)ll*16384]);
    atomicAdd(&hhat[b*256 + d], s);
}

// ---------------- h_hat (slow path) ----------------
__global__ __launch_bounds__(1024) void k_hhat(const void* __restrict__ h0,
    const int* __restrict__ slen, float* __restrict__ hhat, const int* __restrict__ flagp)
{
    int isf = flagp[0];
    int b = blockIdx.x;
    int part = threadIdx.x >> 8;
    int d = threadIdx.x & 255;
    int lenb = slen[b];
    float s = 0.f;
    for (int l = part; l < lenb; l += 4)
        s += ldf(h0, (size_t)l*16384 + b*256 + d, isf);
    __shared__ float red[1024];
    red[threadIdx.x] = s;
    __syncthreads();
    if (part == 0)
        hhat[b*256 + d] = (red[d] + red[d+256] + red[d+512] + red[d+768]);
}

// ---------------- fg, og, sg (global-cell small gates) ----------------
__global__ __launch_bounds__(256) void k_small(const void* __restrict__ h0,
    const float* __restrict__ hhat, const void* __restrict__ Sw,
    const void* __restrict__ Su, const void* __restrict__ Sb,
    float* __restrict__ fg, float* __restrict__ og, float* __restrict__ sg,
    const int* __restrict__ flagp, float hs)
{
    int isf = flagp[0];
    int b = blockIdx.x; int d = threadIdx.x;
    __shared__ float hgl[256], hhl[256];
    hgl[d] = ldf(h0, (size_t)16777216 + b*256 + d, isf);
    hhl[d] = hhat[b*256 + d] * hs;
    __syncthreads();
    size_t sw0 = (size_t)d*256, sw1 = (size_t)(256+d)*256, sw2 = (size_t)(512+d)*256;
    size_t su0 = (size_t)d*256, su2 = (size_t)(512+d)*256;
    float a0=0.f,a1=0.f,a2=0.f,a3=0.f,a4=0.f;
    #pragma unroll 4
    for (int h=0; h<256; h+=4){
        float4 w0 = ldf4(Sw, sw0+h, isf);
        float4 u0 = ldf4(Su, su0+h, isf);
        float4 w1 = ldf4(Sw, sw1+h, isf);
        float4 w2 = ldf4(Sw, sw2+h, isf);
        float4 u2 = ldf4(Su, su2+h, isf);
        float g0=hgl[h], g1=hgl[h+1], g2=hgl[h+2], g3=hgl[h+3];
        float q0=hhl[h], q1=hhl[h+1], q2=hhl[h+2], q3=hhl[h+3];
        a0 += g0*w0.x + g1*w0.y + g2*w0.z + g3*w0.w;
        a1 += q0*u0.x + q1*u0.y + q2*u0.z + q3*u0.w;
        a2 += g0*w1.x + g1*w1.y + g2*w1.z + g3*w1.w;
        a3 += g0*w2.x + g1*w2.y + g2*w2.z + g3*w2.w;
        a4 += q0*u2.x + q1*u2.y + q2*u2.z + q3*u2.w;
    }
    int i = b*256 + d;
    fg[i] = sigf(a0 + a1 + ldf(Sb, d, isf));
    sg[i] = a2 + ldf(Sb, 256 + d, isf);
    og[i] = sigf(a3 + a4 + ldf(Sb, 512 + d, isf));
}

// ---------------- hgWvB[b][g*256+d] = hg @ Wv[g].T + Wb ----------------
__global__ __launch_bounds__(256) void k_hgwv(const void* __restrict__ h0,
    const void* __restrict__ Wv, const void* __restrict__ Wb,
    float* __restrict__ hgWvB, const int* __restrict__ flagp)
{
    int isf = flagp[0];
    int b = blockIdx.x, g = blockIdx.y, d = threadIdx.x;
    __shared__ float hgl[256];
    hgl[d] = ldf(h0, (size_t)16777216 + b*256 + d, isf);
    __syncthreads();
    size_t wv = ((size_t)g*256 + d)*256;
    float a = 0.f;
    #pragma unroll 4
    for (int h=0; h<256; h+=4){
        float4 w = ldf4(Wv, wv+h, isf);
        a += hgl[h]*w.x + hgl[h+1]*w.y + hgl[h+2]*w.z + hgl[h+3]*w.w;
    }
    hgWvB[(size_t)b*1792 + g*256 + d] = a + ldf(Wb, g*256 + d, isf);
}

// ---------------- fi softmax num/den via MFMA — fast (bf16 hpad/Subf) ----------------
__global__ __launch_bounds__(256) void k_fi_fast(const unsigned short* __restrict__ hpad,
    const void* __restrict__ c0, const unsigned short* __restrict__ Subf,
    const int* __restrict__ slen, const float* __restrict__ sg,
    float* __restrict__ numv, float* __restrict__ denv, const int* __restrict__ flagp)
{
    int isf = flagp[0];
    __shared__ unsigned short Hs[64*LDH];
    int tid = threadIdx.x;
    int b = blockIdx.x;
    int l0 = blockIdx.y * 64;
    int lenb = slen[b];
    #pragma unroll
    for (int i=0;i<8;i++){
        int c = tid + i*256;
        int r = c >> 5;
        int col = (c & 31) << 3;
        *(us8*)(Hs + r*LDH + col) =
            *(const us8*)(hpad + (size_t)(l0 + r + 2)*16384 + b*256 + col);
    }
    __syncthreads();
    int wv = tid >> 6, lane = tid & 63, qd = lane >> 4, lc = lane & 15;
    f32x4 zero4 = {0.f,0.f,0.f,0.f};
    for (int dci=0; dci<4; ++dci){
        int d = (wv*4 + dci) * 16 + lc;
        f32x4 acc[4];
        #pragma unroll
        for (int t=0;t<4;t++) acc[t] = zero4;
        #pragma unroll
        for (int ks=0; ks<8; ++ks){
            int k0 = ks*32 + qd*8;
            bf16x8 bb = *(const bf16x8*)(Subf + (size_t)d*256 + k0);
            #pragma unroll
            for (int lt=0; lt<4; ++lt){
                bf16x8 aa = *(const bf16x8*)(Hs + (lt*16 + lc)*LDH + k0);
                acc[lt] = __builtin_amdgcn_mfma_f32_16x16x32_bf16(aa, bb, acc[lt], 0, 0, 0);
            }
        }
        float sgv = sg[b*256 + d];
        float pn = 0.f, pd = 0.f;
        #pragma unroll
        for (int lt=0; lt<4; ++lt){
            #pragma unroll
            for (int r=0; r<4; ++r){
                int l = l0 + lt*16 + qd*4 + r;
                if (l < lenb){
                    float e = __expf(sigf(acc[lt][r] + sgv));
                    pd += e;
                    pn += e * ldf(c0, (size_t)l*16384 + b*256 + d, isf);
                }
            }
        }
        pn += __shfl_xor(pn, 16); pn += __shfl_xor(pn, 32);
        pd += __shfl_xor(pd, 16); pd += __shfl_xor(pd, 32);
        if (qd == 0){
            atomicAdd(&numv[b*256 + d], pn);
            atomicAdd(&denv[b*256 + d], pd);
        }
    }
}

// ---------------- fi (slow path, raw inputs) ----------------
__global__ __launch_bounds__(256) void k_fi(const void* __restrict__ h0,
    const void* __restrict__ c0, const void* __restrict__ Su,
    const int* __restrict__ slen, const float* __restrict__ sg,
    float* __restrict__ numv, float* __restrict__ denv, const int* __restrict__ flagp)
{
    int isf = flagp[0];
    __shared__ unsigned short Hs[64*LDH];
    int tid = threadIdx.x;
    int b = blockIdx.x;
    int l0 = blockIdx.y * 64;
    int lenb = slen[b];
    #pragma unroll
    for (int i=0;i<8;i++){
        int c = tid + i*256;
        int r = c >> 5;
        int col = (c & 31) << 3;
        int l = l0 + r;
        us8 v = {0,0,0,0,0,0,0,0};
        if (l < lenb)
            v = ld8(h0, (size_t)l*16384 + b*256 + col, isf);
        *(us8*)(Hs + r*LDH + col) = v;
    }
    __syncthreads();
    int wv = tid >> 6, lane = tid & 63, qd = lane >> 4, lc = lane & 15;
    f32x4 zero4 = {0.f,0.f,0.f,0.f};
    for (int dci=0; dci<4; ++dci){
        int d = (wv*4 + dci) * 16 + lc;
        f32x4 acc[4];
        #pragma unroll
        for (int t=0;t<4;t++) acc[t] = zero4;
        #pragma unroll
        for (int ks=0; ks<8; ++ks){
            int k0 = ks*32 + qd*8;
            union { us8 u; bf16x8 b; } cv; cv.u = ld8(Su, (size_t)65536 + (size_t)d*256 + k0, isf);
            bf16x8 bb = cv.b;
            #pragma unroll
            for (int lt=0; lt<4; ++lt){
                bf16x8 aa = *(const bf16x8*)(Hs + (lt*16 + lc)*LDH + k0);
                acc[lt] = __builtin_amdgcn_mfma_f32_16x16x32_bf16(aa, bb, acc[lt], 0, 0, 0);
            }
        }
        float sgv = sg[b*256 + d];
        float pn = 0.f, pd = 0.f;
        #pragma unroll
        for (int lt=0; lt<4; ++lt){
            #pragma unroll
            for (int r=0; r<4; ++r){
                int l = l0 + lt*16 + qd*4 + r;
                if (l < lenb){
                    float e = __expf(sigf(acc[lt][r] + sgv));
                    pd += e;
                    pn += e * ldf(c0, (size_t)l*16384 + b*256 + d, isf);
                }
            }
        }
        pn += __shfl_xor(pn, 16); pn += __shfl_xor(pn, 32);
        pd += __shfl_xor(pd, 16); pd += __shfl_xor(pd, 32);
        if (qd == 0){
            atomicAdd(&numv[b*256 + d], pn);
            atomicAdd(&denv[b*256 + d], pd);
        }
    }
}

// ---------------- finalize global cell ----------------
__global__ __launch_bounds__(256) void k_cg(const void* __restrict__ c0,
    const float* __restrict__ fg, const float* __restrict__ og,
    const float* __restrict__ numv, const float* __restrict__ denv,
    float* __restrict__ outh, float* __restrict__ outc,
    const int* __restrict__ flagp)
{
    int isf = flagp[0];
    int i = blockIdx.x*256 + threadIdx.x;
    float cg1 = ldf(c0, (size_t)16777216 + i, isf);
    float cg = fg[i]*cg1 + numv[i]/denv[i];
    float hg = og[i]*tanhfast(cg);
    outh[(size_t)16777216 + i] = hg;
    outc[(size_t)16777216 + i] = cg;
}

// ================= fast main GEMM: BM=256/BK=32, cooperative LDS staging ========
// grid (16, 256): bx = d-tile (d0 = bx*16), by = m-tile (m0 = by*256).
// Round-0's proven schedule (sync; stage both A+B via global_load_lds; sync; compute)
// with a 2x bigger M-tile: each wave owns 64 rows -> 28 MFMA : 11 ds_read per phase
// (vs 14:9 at BM=128). Per-CU LDS traffic drops ~0.66x, B-read redundancy halves.
// Swizzle: 4 chunks/row, mask(row) = (row>>1)&3, applied on pre-swizzled global
// source and identically on ds_read (2-way bank aliasing = free).
__global__ __launch_bounds__(256, 2) void k_main_fast(
    const unsigned short* __restrict__ hpad, const unsigned short* __restrict__ srcpad,
    const unsigned short* __restrict__ Wcat, const void* __restrict__ c0,
    const int* __restrict__ slen, const float* __restrict__ hgWvB,
    float* __restrict__ outh, float* __restrict__ outc, const int* __restrict__ flagp)
{
    int isf = flagp[0];
    __shared__ unsigned short As[8192];   // 256 rows x 32 shorts = 16 KiB
    __shared__ unsigned short Bs[3584];   // 112 rows x 32 shorts = 7 KiB
    int tid = threadIdx.x;
    int d0 = blockIdx.x * 16;
    int m0 = blockIdx.y * 256;
    int wv = tid >> 6, lane = tid & 63, qd = lane >> 4, lc = lane & 15;

    // ---- staging precompute: pre-swizzled global source, mask(row) = (row>>1)&3
    int aoffH[4], aoffS[4];
    #pragma unroll
    for (int i=0;i<4;i++){
        int c = i*256 + tid;          // A chunk 0..1023 (16B each, 4/row)
        int r = c >> 2, sl = c & 3;
        int col = ((sl ^ ((r >> 1) & 3)) << 3);
        aoffH[i] = r*256 + col;
        aoffS[i] = r*320 + col;
    }
    int boff0s, boff1s;
    {
        int c = tid, r = c >> 2, sl = c & 3;
        boff0s = r*32 + ((sl ^ ((r >> 1) & 3)) << 3);
        c = 256 + tid; r = c >> 2; sl = c & 3;   // rows 64..111 (tid<192)
        boff1s = r*32 + ((sl ^ ((r >> 1) & 3)) << 3);
    }
    const unsigned short* gB  = Wcat + (size_t)blockIdx.x * 50 * 3584;
    const unsigned short* gAh = hpad + (size_t)m0 * 256;
    const unsigned short* gAs = srcpad + (size_t)m0 * 320;

    // ---- read offsets: row masks reduce to (lc>>1)&3 for both A and B rows
    int xch = (qd ^ ((lc >> 1) & 3)) << 3;
    int ra0 = (wv*64 +  0 + lc)*32 + xch;
    int ra1 = (wv*64 + 16 + lc)*32 + xch;
    int ra2 = (wv*64 + 32 + lc)*32 + xch;
    int ra3 = (wv*64 + 48 + lc)*32 + xch;
    int rb0 = ( 0 + lc)*32 + xch;
    int rb1 = (16 + lc)*32 + xch;
    int rb2 = (32 + lc)*32 + xch;
    int rb3 = (48 + lc)*32 + xch;
    int rb4 = (64 + lc)*32 + xch;
    int rb5 = (80 + lc)*32 + xch;
    int rb6 = (96 + lc)*32 + xch;

    f32x4 zero4 = {0.f,0.f,0.f,0.f};
    f32x4 acc[4][7];
    #pragma unroll
    for (int a=0;a<4;a++)
        #pragma unroll
        for (int g=0;g<7;g++) acc[a][g] = zero4;

    for (int h=0; h<50; ++h){
        __syncthreads();
        // stage A (4 x global_load_lds / thread; 16 KiB tile)
        if (h < 40){
            const unsigned short* ga = gAh + (h>>3)*16384 + ((h&7)<<5);
            #pragma unroll
            for (int i=0;i<4;i++)
                stage16(ga + aoffH[i], As + i*2048 + wv*512, lane);
        } else {
            const unsigned short* ga = gAs + ((h-40)<<5);
            #pragma unroll
            for (int i=0;i<4;i++)
                stage16(ga + aoffS[i], As + i*2048 + wv*512, lane);
        }
        // stage B (7 KiB panel; waves 0-2 carry the second issue)
        const unsigned short* gb = gB + h*3584;
        stage16(gb + boff0s, Bs + wv*512, lane);
        if (tid < 192)
            stage16(gb + boff1s, Bs + 2048 + wv*512, lane);
        __syncthreads();
        // compute: 11 ds_read_b128 -> 28 MFMA
        bf16x8 va0 = *(const bf16x8*)(As + ra0);
        bf16x8 va1 = *(const bf16x8*)(As + ra1);
        bf16x8 va2 = *(const bf16x8*)(As + ra2);
        bf16x8 va3 = *(const bf16x8*)(As + ra3);
        __builtin_amdgcn_s_setprio(1);
        {
            bf16x8 vb = *(const bf16x8*)(Bs + rb0);
            acc[0][0] = __builtin_amdgcn_mfma_f32_16x16x32_bf16(va0, vb, acc[0][0],0,0,0);
            acc[1][0] = __builtin_amdgcn_mfma_f32_16x16x32_bf16(va1, vb, acc[1][0],0,0,0);
            acc[2][0] = __builtin_amdgcn_mfma_f32_16x16x32_bf16(va2, vb, acc[2][0],0,0,0);
            acc[3][0] = __builtin_amdgcn_mfma_f32_16x16x32_bf16(va3, vb, acc[3][0],0,0,0);
        }
        {
            bf16x8 vb = *(const bf16x8*)(Bs + rb1);
            acc[0][1] = __builtin_amdgcn_mfma_f32_16x16x32_bf16(va0, vb, acc[0][1],0,0,0);
            acc[1][1] = __builtin_amdgcn_mfma_f32_16x16x32_bf16(va1, vb, acc[1][1],0,0,0);
            acc[2][1] = __builtin_amdgcn_mfma_f32_16x16x32_bf16(va2, vb, acc[2][1],0,0,0);
            acc[3][1] = __builtin_amdgcn_mfma_f32_16x16x32_bf16(va3, vb, acc[3][1],0,0,0);
        }
        {
            bf16x8 vb = *(const bf16x8*)(Bs + rb2);
            acc[0][2] = __builtin_amdgcn_mfma_f32_16x16x32_bf16(va0, vb, acc[0][2],0,0,0);
            acc[1][2] = __builtin_amdgcn_mfma_f32_16x16x32_bf16(va1, vb, acc[1][2],0,0,0);
            acc[2][2] = __builtin_amdgcn_mfma_f32_16x16x32_bf16(va2, vb, acc[2][2],0,0,0);
            acc[3][2] = __builtin_amdgcn_mfma_f32_16x16x32_bf16(va3, vb, acc[3][2],0,0,0);
        }
        {
            bf16x8 vb = *(const bf16x8*)(Bs + rb3);
            acc[0][3] = __builtin_amdgcn_mfma_f32_16x16x32_bf16(va0, vb, acc[0][3],0,0,0);
            acc[1][3] = __builtin_amdgcn_mfma_f32_16x16x32_bf16(va1, vb, acc[1][3],0,0,0);
            acc[2][3] = __builtin_amdgcn_mfma_f32_16x16x32_bf16(va2, vb, acc[2][3],0,0,0);
            acc[3][3] = __builtin_amdgcn_mfma_f32_16x16x32_bf16(va3, vb, acc[3][3],0,0,0);
        }
        {
            bf16x8 vb = *(const bf16x8*)(Bs + rb4);
            acc[0][4] = __builtin_amdgcn_mfma_f32_16x16x32_bf16(va0, vb, acc[0][4],0,0,0);
            acc[1][4] = __builtin_amdgcn_mfma_f32_16x16x32_bf16(va1, vb, acc[1][4],0,0,0);
            acc[2][4] = __builtin_amdgcn_mfma_f32_16x16x32_bf16(va2, vb, acc[2][4],0,0,0);
            acc[3][4] = __builtin_amdgcn_mfma_f32_16x16x32_bf16(va3, vb, acc[3][4],0,0,0);
        }
        {
            bf16x8 vb = *(const bf16x8*)(Bs + rb5);
            acc[0][5] = __builtin_amdgcn_mfma_f32_16x16x32_bf16(va0, vb, acc[0][5],0,0,0);
            acc[1][5] = __builtin_amdgcn_mfma_f32_16x16x32_bf16(va1, vb, acc[1][5],0,0,0);
            acc[2][5] = __builtin_amdgcn_mfma_f32_16x16x32_bf16(va2, vb, acc[2][5],0,0,0);
            acc[3][5] = __builtin_amdgcn_mfma_f32_16x16x32_bf16(va3, vb, acc[3][5],0,0,0);
        }
        {
            bf16x8 vb = *(const bf16x8*)(Bs + rb6);
            acc[0][6] = __builtin_amdgcn_mfma_f32_16x16x32_bf16(va0, vb, acc[0][6],0,0,0);
            acc[1][6] = __builtin_amdgcn_mfma_f32_16x16x32_bf16(va1, vb, acc[1][6],0,0,0);
            acc[2][6] = __builtin_amdgcn_mfma_f32_16x16x32_bf16(va2, vb, acc[2][6],0,0,0);
            acc[3][6] = __builtin_amdgcn_mfma_f32_16x16x32_bf16(va3, vb, acc[3][6],0,0,0);
        }
        __builtin_amdgcn_s_setprio(0);
    }

    // Fused gate epilogue (4 m-subtiles per wave)
    int d = d0 + lc;
    #pragma unroll
    for (int mt=0; mt<4; ++mt){
        #pragma unroll
        for (int r=0; r<4; ++r){
            int m = m0 + wv*64 + mt*16 + qd*4 + r;
            int l = m >> 6, b = m & 63;
            size_t oi = (size_t)m*256 + d;
            int lenb = slen[b];
            float hw = 0.f, cw = 0.f;
            if (l < lenb){
                const float* hv = hgWvB + (size_t)b*1792 + d;
                float p0 = acc[mt][0][r] + hv[0];
                float p1 = acc[mt][1][r] + hv[256];
                float p2 = acc[mt][2][r] + hv[512];
                float p3 = acc[mt][3][r] + hv[768];
                float p4 = acc[mt][4][r] + hv[1024];
                float p5 = acc[mt][5][r] + hv[1280];
                float p6 = acc[mt][6][r] + hv[1536];
                float e_l = __expf(sigf(p1));
                float e_f = __expf(sigf(p3));
                float e_r = __expf(sigf(p2));
                float e_s = __expf(sigf(p4));
                float e_i = __expf(sigf(p0));
                float S = e_l + e_f + e_r + e_s + e_i;
                float u_ = tanhfast(p6);
                float cl = (l >= 1) ? ldf(c0, oi - 16384, isf) : 0.f;
                float cc = ldf(c0, oi, isf);
                float cr = (l + 1 < lenb) ? ldf(c0, oi + 16384, isf) : 0.f;
                float cg1 = ldf(c0, (size_t)16777216 + b*256 + d, isf);
                cw = (e_l*cl + e_f*cc + e_r*cr + e_s*cg1 + e_i*u_) / S;
                hw = sigf(p5) * tanhfast(cw);
            }
            outh[oi] = hw;
            outc[oi] = cw;
        }
    }
}

// ================= slow main GEMM (fallback, raw inputs) =================
__global__ __launch_bounds__(256) void k_main(
    const void* __restrict__ src, const void* __restrict__ h0,
    const void* __restrict__ c0, const void* __restrict__ Ww,
    const void* __restrict__ Wu, const int* __restrict__ slen,
    const float* __restrict__ hgWvB,
    float* __restrict__ outh, float* __restrict__ outc,
    const int* __restrict__ flagp)
{
    int isf = flagp[0];
    __shared__ unsigned short As[128*LDK];
    __shared__ unsigned short Bs[112*LDK];
    int tid = threadIdx.x;
    int m0 = blockIdx.x * 128;
    int d0 = blockIdx.y * 16;
    int wv = tid >> 6, lane = tid & 63, qd = lane >> 4, lc = lane & 15;

    int ar[4], acol[4], al[4], ab[4], alen[4];
    #pragma unroll
    for (int i=0;i<4;i++){
        int c = tid + i*256;
        ar[i] = c >> 3; acol[i] = (c & 7) << 3;
        int m = m0 + ar[i];
        al[i] = m >> 6; ab[i] = m & 63;
        alen[i] = slen[ab[i]];
    }

    f32x4 zero4 = {0.f,0.f,0.f,0.f};
    f32x4 acc[2][7];
    #pragma unroll
    for (int a=0;a<2;a++)
        #pragma unroll
        for (int g=0;g<7;g++) acc[a][g] = zero4;

    for (int kt=0; kt<25; ++kt){
        __syncthreads();
        if (kt < 20){
            int j = kt >> 2;
            int koff = (kt & 3) << 6;
            #pragma unroll
            for (int i=0;i<4;i++){
                int lp = al[i] + j - 2;
                us8 v = {0,0,0,0,0,0,0,0};
                if ((unsigned)lp < 1024u && lp < alen[i])
                    v = ld8(h0, (size_t)lp*16384 + ab[i]*256 + koff + acol[i], isf);
                *(us8*)(As + ar[i]*LDK + acol[i]) = v;
            }
            #pragma unroll
            for (int i=0;i<4;i++){
                int c = tid + i*256;
                if (c < 896){
                    int rr = c >> 3, col = (c & 7) << 3;
                    int g = rr >> 4, d = d0 + (rr & 15);
                    *(us8*)(Bs + rr*LDK + col) =
                        ld8(Ww, ((size_t)g*256 + d)*1280 + j*256 + koff + col, isf);
                }
            }
        } else {
            int w0 = (kt - 20) << 6;
            #pragma unroll
            for (int i=0;i<16;i++){
                int c = tid + i*256;
                int r = c >> 5, wi = (c & 31) << 1;
                int w = w0 + wi;
                int m = m0 + r;
                unsigned int v = 0;
                if (w < 300) v = ld2(src, (size_t)m*300 + w, isf);
                *(unsigned int*)(As + r*LDK + wi) = v;
            }
            #pragma unroll
            for (int i=0;i<14;i++){
                int c = tid + i*256;
                int rr = c >> 5, wi = (c & 31) << 1;
                int w = w0 + wi;
                int g = rr >> 4, d = d0 + (rr & 15);
                unsigned int v = 0;
                if (w < 300) v = ld2(Wu, ((size_t)g*256 + d)*300 + w, isf);
                *(unsigned int*)(Bs + rr*LDK + wi) = v;
            }
        }
        __syncthreads();
        #pragma unroll
        for (int ks=0; ks<2; ++ks){
            int k0 = (ks << 5) + (qd << 3);
            bf16x8 a0 = *(const bf16x8*)(As + (wv*32 + lc)*LDK + k0);
            bf16x8 a1 = *(const bf16x8*)(As + (wv*32 + 16 + lc)*LDK + k0);
            #pragma unroll
            for (int g=0; g<7; ++g){
                bf16x8 bg = *(const bf16x8*)(Bs + (g*16 + lc)*LDK + k0);
                acc[0][g] = __builtin_amdgcn_mfma_f32_16x16x32_bf16(a0, bg, acc[0][g], 0,0,0);
                acc[1][g] = __builtin_amdgcn_mfma_f32_16x16x32_bf16(a1, bg, acc[1][g], 0,0,0);
            }
        }
    }

    int d = d0 + lc;
    #pragma unroll
    for (int mt=0; mt<2; ++mt){
        #pragma unroll
        for (int r=0; r<4; ++r){
            int m = m0 + wv*32 + mt*16 + qd*4 + r;
            int l = m >> 6, b = m & 63;
            size_t oi = (size_t)m*256 + d;
            int lenb = slen[b];
            float hw = 0.f, cw = 0.f;
            if (l < lenb){
                const float* hv = hgWvB + (size_t)b*1792 + d;
                float p0 = acc[mt][0][r] + hv[0];
                float p1 = acc[mt][1][r] + hv[256];
                float p2 = acc[mt][2][r] + hv[512];
                float p3 = acc[mt][3][r] + hv[768];
                float p4 = acc[mt][4][r] + hv[1024];
                float p5 = acc[mt][5][r] + hv[1280];
                float p6 = acc[mt][6][r] + hv[1536];
                float e_l = __expf(sigf(p1));
                float e_f = __expf(sigf(p3));
                float e_r = __expf(sigf(p2));
                float e_s = __expf(sigf(p4));
                float e_i = __expf(sigf(p0));
                float S = e_l + e_f + e_r + e_s + e_i;
                float u_ = tanhfast(p6);
                float cl = (l >= 1) ? ldf(c0, oi - 16384, isf) : 0.f;
                float cc = ldf(c0, oi, isf);
                float cr = (l + 1 < lenb) ? ldf(c0, oi + 16384, isf) : 0.f;
                float cg1 = ldf(c0, (size_t)16777216 + b*256 + d, isf);
                cw = (e_l*cl + e_f*cc + e_r*cr + e_s*cg1 + e_i*u_) / S;
                hw = sigf(p5) * tanhfast(cw);
            }
            outh[oi] = hw;
            outc[oi] = cw;
        }
    }
}

extern "C" void kernel_launch(void* const* d_in, const int* in_sizes, int n_in,
                              void* d_out, int out_size, void* d_ws, size_t ws_size,
                              hipStream_t stream)
{
    const void* src = d_in[0];
    const void* h0  = d_in[1];
    const void* c0  = d_in[2];
    const void* Ww  = d_in[3];
    const void* Wu  = d_in[4];
    const void* Wv  = d_in[5];
    const void* Wb  = d_in[6];
    const void* Sw  = d_in[7];
    const void* Su  = d_in[8];
    const void* Sb  = d_in[9];
    const int* slen = (const int*)d_in[10];

    float* outh = (float*)d_out;
    float* outc = outh + (size_t)1025*64*256;

    float* ws    = (float*)d_ws;
    float* numv  = ws;
    float* denv  = ws + 16384;
    float* hhat  = ws + 32768;
    float* fg    = ws + 49152;
    float* og    = ws + 65536;
    float* sg    = ws + 81920;
    float* hgWvB = ws + 98304;            // 64*1792 floats -> ends 212992
    int*   flag  = (int*)(ws + 212992);   // 16 floats reserved

    unsigned short* bfbase = (unsigned short*)(ws + 213024);
    unsigned short* hpad   = bfbase;                       // 1028*16384
    unsigned short* srcpad = bfbase + (size_t)16842752;    // 65536*320
    unsigned short* Wcat   = bfbase + (size_t)37814272;    // 16*50*112*32 = 2867200
    unsigned short* Subf   = bfbase + (size_t)40681472;    // 256*256
    const size_t NEED = 852096 + (size_t)40747008*2;       // 82,346,112 B

    hipLaunchKernelGGL(k_detect, dim3(1), dim3(256), 0, stream, h0, flag);
    hipMemsetAsync(ws, 0, (size_t)3*16384*sizeof(float), stream);   // numv, denv, hhat

    if (ws_size >= NEED){
        hipLaunchKernelGGL(k_conv_h,  dim3(8,1028), dim3(256), 0, stream, h0, slen, hpad, flag);
        hipLaunchKernelGGL(k_conv_src, dim3(10240), dim3(256), 0, stream, src, srcpad, flag);
        hipLaunchKernelGGL(k_conv_w,   dim3(1400),  dim3(256), 0, stream, Ww, Wu, Wcat, flag);
        hipLaunchKernelGGL(k_conv_su,  dim3(32),    dim3(256), 0, stream, Su, Subf, flag);
        hipLaunchKernelGGL(k_hhat_fast, dim3(64,8), dim3(256), 0, stream, hpad, hhat);
        hipLaunchKernelGGL(k_small, dim3(64), dim3(256), 0, stream, h0, hhat, Sw, Su, Sb,
                           fg, og, sg, flag, 1.0f/1024.0f);
        hipLaunchKernelGGL(k_hgwv, dim3(64,7), dim3(256), 0, stream, h0, Wv, Wb, hgWvB, flag);
        hipLaunchKernelGGL(k_fi_fast, dim3(64,16), dim3(256), 0, stream, hpad, c0, Subf, slen,
                           sg, numv, denv, flag);
        hipLaunchKernelGGL(k_cg, dim3(64), dim3(256), 0, stream, c0, fg, og, numv, denv,
                           outh, outc, flag);
        hipLaunchKernelGGL(k_main_fast, dim3(16,256), dim3(256), 0, stream,
                           hpad, srcpad, Wcat, c0, slen, hgWvB, outh, outc, flag);
    } else {
        hipLaunchKernelGGL(k_hhat, dim3(64), dim3(1024), 0, stream, h0, slen, hhat, flag);
        hipLaunchKernelGGL(k_small, dim3(64), dim3(256), 0, stream, h0, hhat, Sw, Su, Sb,
                           fg, og, sg, flag, 1.0f/1024.0f);
        hipLaunchKernelGGL(k_hgwv, dim3(64,7), dim3(256), 0, stream, h0, Wv, Wb, hgWvB, flag);
        hipLaunchKernelGGL(k_fi, dim3(64,16), dim3(256), 0, stream, h0, c0, Su, slen,
                           sg, numv, denv, flag);
        hipLaunchKernelGGL(k_cg, dim3(64), dim3(256), 0, stream, c0, fg, og, numv, denv,
                           outh, outc, flag);
        hipLaunchKernelGGL(k_main, dim3(512,16), dim3(256), 0, stream,
                           src, h0, c0, Ww, Wu, slen, hgWvB, outh, outc, flag);
    }
}